// Round 11
// baseline (2998.206 us; speedup 1.0000x reference)
//
#include <hip/hip_runtime.h>

#define B_   128
#define T_   128
#define DIN  64
#define H_   1024
#define NBLK 256
#define NTHR 512

typedef _Float16 f16;
typedef _Float16 half8 __attribute__((ext_vector_type(8)));
typedef float float4v __attribute__((ext_vector_type(4)));

// Work split: block b -> cg = b>>1 (8 h-cols: cg*8..cg*8+7), mh = b&1 (64 rows).
// h layout: region per block, h(m, col) at buf[b*512 + (m&63)*8 + (col&7)].
// Each block writes ONE contiguous 1KB region (exclusive lines, no RMW).
// Readers: window j, lane(col,quad): one dwordx4 at region (j*4+quad)*2+mh.
//
// LDS layout:
//  W1s : f16[2 nt][34 ch][512]   (Whh1 + Wih1 fragments)     69632 B
//  W2s : f16[2 nt][32 ch][512]   (Wih2 vs h1)                65536 B
//  Sg1 : float[64][33]                                        8448 B
//  Sg2 : float[64][33]                                        8448 B
//  c1,c2: float[512] each                                     4096 B
//  bs1,bs2: float[32] each                                     256 B   total 156416
// Whh2 (vs h2) lives in 128 VGPRs/lane (32 x half8), R8-proven.
#define OFF_W2   69632
#define OFF_SG1  135168
#define OFF_SG2  143616
#define OFF_C1   152064
#define OFF_C2   154112
#define OFF_B1   156160
#define OFF_B2   156288
#define SMEM_BYTES 156416

// Barrier state S (unsigned[2048], 8 KB), one 128-B line per hot word:
//  S[x*32]         : per-XCD ticket
//  S[512]          : central XCD counter
//  S[544]          : release word            (polled by <=8 XCD leaders)
//  S[576 + x*32]   : per-XCD go flag         (polled by <=31 blocks)
//  S[1088 + x*32]  : per-XCD inv-done flag   (polled by 1 leader)
//  S[1600 + x]     : per-XCD block count     (preamble only)

struct Params {
  const float *x, *Wih1, *Whh1, *bih1, *bhh1, *Wih2, *Whh2, *bih2, *bhh2,
              *Wlin, *blin, *Whio, *bhio;
  const int* fut;
  float* out;
  f16 *x16, *h1a, *h1b, *h2a, *h2b, *ob;
  unsigned *arrive, *rel;
  unsigned *S;
};

__device__ __forceinline__ float sigm(float v) { return 1.f / (1.f + __expf(-v)); }
__device__ __forceinline__ float tanh_(float v) { return 2.f / (1.f + __expf(-2.f * v)) - 1.f; }

__device__ __forceinline__ unsigned get_xcc() {
  unsigned x;
  asm volatile("s_getreg_b32 %0, hwreg(HW_REG_XCC_ID)" : "=s"(x));
  return x & 15u;
}

// ---- slow barrier (preamble only) -----------------------------------------
__device__ __forceinline__ void grid_sync(unsigned* arrive, unsigned* rel, unsigned ph) {
  __syncthreads();
  const int tid = threadIdx.x, bid = blockIdx.x;
  if (bid == 0) {
    if (tid > 0 && tid < NBLK) {
      while (__hip_atomic_load(&arrive[tid], __ATOMIC_RELAXED, __HIP_MEMORY_SCOPE_AGENT) != ph)
        __builtin_amdgcn_s_sleep(8);
    }
    __syncthreads();
    if (tid == 0)
      __hip_atomic_store(rel, ph, __ATOMIC_RELEASE, __HIP_MEMORY_SCOPE_AGENT);
  } else {
    if (tid == 0) {
      __hip_atomic_store(&arrive[bid], ph, __ATOMIC_RELEASE, __HIP_MEMORY_SCOPE_AGENT);
      while (__hip_atomic_load(rel, __ATOMIC_RELAXED, __HIP_MEMORY_SCOPE_AGENT) != ph)
        __builtin_amdgcn_s_sleep(8);
    }
  }
  __syncthreads();
  __builtin_amdgcn_fence(__ATOMIC_ACQUIRE, "agent");
}

// ---- fast barrier v4 (R8/R10-proven): L2-inv hoisted to arrive-time -------
__device__ __forceinline__ void fast_sync(unsigned* S, unsigned x, unsigned xtotal,
                                          unsigned nxcd, unsigned ph) {
  __syncthreads();
  if (threadIdx.x == 0) {
    unsigned t = __hip_atomic_fetch_add(&S[x * 32], 1u, __ATOMIC_RELAXED, __HIP_MEMORY_SCOPE_AGENT);
    bool leader = (t % xtotal == 0u);
    if ((t + 1u) % xtotal == 0u) {
      unsigned c = __hip_atomic_fetch_add(&S[512], 1u, __ATOMIC_RELAXED, __HIP_MEMORY_SCOPE_AGENT);
      if ((c + 1u) % nxcd == 0u)
        __hip_atomic_store(&S[544], ph, __ATOMIC_RELAXED, __HIP_MEMORY_SCOPE_AGENT);
      asm volatile("buffer_inv sc0 sc1\n\ts_waitcnt vmcnt(0)" ::: "memory");
      __hip_atomic_store(&S[1088 + x * 32], ph, __ATOMIC_RELAXED, __HIP_MEMORY_SCOPE_AGENT);
    }
    if (leader) {
      while (__hip_atomic_load(&S[544], __ATOMIC_RELAXED, __HIP_MEMORY_SCOPE_AGENT) != ph)
        __builtin_amdgcn_s_sleep(1);
      while (__hip_atomic_load(&S[1088 + x * 32], __ATOMIC_RELAXED, __HIP_MEMORY_SCOPE_AGENT) != ph)
        __builtin_amdgcn_s_sleep(1);
      __hip_atomic_store(&S[576 + x * 32], ph, __ATOMIC_RELAXED, __HIP_MEMORY_SCOPE_AGENT);
      asm volatile("buffer_inv sc0\n\ts_waitcnt vmcnt(0)" ::: "memory");
    } else {
      while (__hip_atomic_load(&S[576 + x * 32], __ATOMIC_RELAXED, __HIP_MEMORY_SCOPE_AGENT) != ph)
        __builtin_amdgcn_s_sleep(2);
      asm volatile("buffer_inv sc0\n\ts_waitcnt vmcnt(0)" ::: "memory");
    }
  }
  __syncthreads();
}

__global__ void __launch_bounds__(NTHR, 2) lstm_k(Params p) {
  extern __shared__ char smem[];
  f16*   W1s  = (f16*)(smem);
  f16*   W2s  = (f16*)(smem + OFF_W2);
  float* Sg1  = (float*)(smem + OFF_SG1);
  float* Sg2  = (float*)(smem + OFF_SG2);
  float* c1   = (float*)(smem + OFF_C1);
  float* c2   = (float*)(smem + OFF_C2);
  float* bs1  = (float*)(smem + OFF_B1);
  float* bs2  = (float*)(smem + OFF_B2);

  const int tid = threadIdx.x, bid = blockIdx.x;
  const int cg  = bid >> 1;          // column group: h-cols cg*8..cg*8+7
  const int mh  = bid & 1;           // M-half: rows mh*64..mh*64+63
  const int fut = p.fut[0];
  const unsigned xcc = get_xcc();
  unsigned* S = p.S;

  // wave geometry
  const int lane = tid & 63, wv = tid >> 6;
  const int col = lane & 15, quad = lane >> 4;
  const int mt = wv & 3;             // m-tile within the 64-row half
  const int nt = wv >> 2;            // n-tile: gate-rows nt*16..nt*16+15
  const int mg = mh * 64 + mt * 16 + col;       // global batch row
  // h read base: region (j*4+quad)*2+mh, offset (mt*16+col)*8
  const int hbase = (quad * 2 + mh) * 512 + (mt * 16 + col) * 8;

  if (bid == 0) {
    for (int i = tid; i < 2048; i += NTHR)
      __hip_atomic_store(&S[i], 0u, __ATOMIC_RELAXED, __HIP_MEMORY_SCOPE_AGENT);
  }

  // ---------------- preamble ------------------------------------------------
  // W1s[nt][c][r]: gate-row gr=nt*16+colL -> g=gr>>3, cc=gr&7; row=g*H+cg*8+cc
  for (int idx = tid; idx < 2 * 34 * 512; idx += NTHR) {
    int ntl = idx / 17408, rem = idx - ntl * 17408;
    int c = rem >> 9, r = rem & 511;
    int q = r >> 7, colL = (r >> 3) & 15, j = r & 7;
    int k = c * 32 + q * 8 + j;
    int gr = ntl * 16 + colL;
    int row = (gr >> 3) * H_ + cg * 8 + (gr & 7);
    float v = (k < H_) ? p.Whh1[row * H_ + k] : p.Wih1[row * DIN + (k - H_)];
    W1s[idx] = (f16)v;
  }
  for (int idx = tid; idx < 2 * 32 * 512; idx += NTHR) {   // Wih2 (vs h1)
    int ntl = idx >> 14, rem = idx & 16383;
    int c = rem >> 9, r = rem & 511;
    int q = r >> 7, colL = (r >> 3) & 15, j = r & 7;
    int k = c * 32 + q * 8 + j;
    int gr = ntl * 16 + colL;
    int row = (gr >> 3) * H_ + cg * 8 + (gr & 7);
    W2s[idx] = (f16)p.Wih2[row * H_ + k];
  }
  // Whh2 -> 128 VGPRs/lane (B-fragments for this wave's n-tile)
  half8 wreg[32];
  {
    int gr = nt * 16 + col;
    int row2 = (gr >> 3) * H_ + cg * 8 + (gr & 7);
    const float* ws = p.Whh2 + row2 * H_ + quad * 8;
    #pragma unroll
    for (int c = 0; c < 32; ++c) {
      float4v v0 = *(const float4v*)(ws + c * 32);
      float4v v1 = *(const float4v*)(ws + c * 32 + 4);
      half8 t;
      t[0] = (f16)v0[0]; t[1] = (f16)v0[1]; t[2] = (f16)v0[2]; t[3] = (f16)v0[3];
      t[4] = (f16)v1[0]; t[5] = (f16)v1[1]; t[6] = (f16)v1[2]; t[7] = (f16)v1[3];
      wreg[c] = t;
    }
  }
  if (tid < 32) {
    int row = (tid >> 3) * H_ + cg * 8 + (tid & 7);
    bs1[tid] = p.bih1[row] + p.bhh1[row];
    bs2[tid] = p.bih2[row] + p.bhh2[row];
  }
  for (int i = tid; i < 512; i += NTHR) { c1[i] = 0.f; c2[i] = 0.f; }
  for (int i = bid * NTHR + tid; i < B_ * T_ * DIN; i += NBLK * NTHR)
    p.x16[i] = (f16)p.x[i];
  for (int i = bid * NTHR + tid; i < B_ * H_; i += NBLK * NTHR) {
    p.h1a[i] = (f16)0.f; p.h1b[i] = (f16)0.f;
    p.h2a[i] = (f16)0.f; p.h2b[i] = (f16)0.f;
  }

  unsigned ph = 1;
  grid_sync(p.arrive, p.rel, ph);
  if (tid == 0)
    __hip_atomic_fetch_add(&S[1600 + xcc], 1u, __ATOMIC_RELAXED, __HIP_MEMORY_SCOPE_AGENT);
  ++ph;
  grid_sync(p.arrive, p.rel, ph);

  unsigned xtotal = __hip_atomic_load(&S[1600 + xcc], __ATOMIC_RELAXED, __HIP_MEMORY_SCOPE_AGENT);
  unsigned nxcd = 0;
  for (int i = 0; i < 16; ++i)
    nxcd += (__hip_atomic_load(&S[1600 + i], __ATOMIC_RELAXED, __HIP_MEMORY_SCOPE_AGENT) != 0u);

  auto gsync = [&]() { ++ph; fast_sync(S, xcc, xtotal, nxcd, ph); };

  const float b1v = bs1[nt * 16 + col], b2v = bs2[nt * 16 + col];
  const f16* W1f = W1s + nt * (34 * 512) + lane * 8;
  const f16* W2f = W2s + nt * (32 * 512) + lane * 8;

  f16 *h1c = p.h1a, *h1n = p.h1b, *h2c = p.h2a, *h2n = p.h2b;

  auto ldwin = [&](const f16* hX, int j) -> half8 {
    return *(const half8*)(hX + hbase + j * 4096);
  };

  auto lstm_pw = [&](const float* Sgb, float* cst, f16* hn) {
    int r = tid >> 3, c8 = tid & 7;
    float gi = Sgb[r * 33 + c8],      gf = Sgb[r * 33 + 8 + c8];
    float gg = Sgb[r * 33 + 16 + c8], go = Sgb[r * 33 + 24 + c8];
    float cn = sigm(gf) * cst[tid] + sigm(gi) * tanh_(gg);
    cst[tid] = cn;
    f16 hv = (f16)(sigm(go) * tanh_(cn));
    // exclusive region, contiguous per wave -> coalesced full-line writes
    __hip_atomic_store((unsigned short*)(hn + bid * 512 + tid),
                       __builtin_bit_cast(unsigned short, hv),
                       __ATOMIC_RELAXED, __HIP_MEMORY_SCOPE_AGENT);
  };

  // fused phase: gates1(t+1) [l1] and gates2(t) [l2], both keyed on h1c
  auto phase = [&](bool l1, bool l2, const f16* xp, int xstr) {
    float4v a1 = {b1v, b1v, b1v, b1v};
    float4v a2 = {b2v, b2v, b2v, b2v};

    if (l1) {   // x part (row-major, cached)
      half8 ax0 = *(const half8*)(xp + mg * xstr + quad * 8);
      half8 ax1 = *(const half8*)(xp + mg * xstr + 32 + quad * 8);
      a1 = __builtin_amdgcn_mfma_f32_16x16x32_f16(ax0, *(const half8*)(W1f + 32 * 512), a1, 0, 0, 0);
      a1 = __builtin_amdgcn_mfma_f32_16x16x32_f16(ax1, *(const half8*)(W1f + 33 * 512), a1, 0, 0, 0);
    }
    if (l1 && l2) {
      #pragma unroll 4
      for (int j = 0; j < 32; ++j) {
        half8 aw = ldwin(h1c, j);
        a1 = __builtin_amdgcn_mfma_f32_16x16x32_f16(aw, *(const half8*)(W1f + j * 512), a1, 0, 0, 0);
        a2 = __builtin_amdgcn_mfma_f32_16x16x32_f16(aw, *(const half8*)(W2f + j * 512), a2, 0, 0, 0);
      }
    } else if (l1) {
      #pragma unroll 4
      for (int j = 0; j < 32; ++j) {
        half8 aw = ldwin(h1c, j);
        a1 = __builtin_amdgcn_mfma_f32_16x16x32_f16(aw, *(const half8*)(W1f + j * 512), a1, 0, 0, 0);
      }
    } else {
      #pragma unroll 4
      for (int j = 0; j < 32; ++j) {
        half8 aw = ldwin(h1c, j);
        a2 = __builtin_amdgcn_mfma_f32_16x16x32_f16(aw, *(const half8*)(W2f + j * 512), a2, 0, 0, 0);
      }
    }
    if (l2) {   // h2 x Whh2 (register B-operands)
      #pragma unroll 4
      for (int j = 0; j < 32; ++j) {
        half8 aw = ldwin(h2c, j);
        a2 = __builtin_amdgcn_mfma_f32_16x16x32_f16(aw, wreg[j], a2, 0, 0, 0);
      }
    }

    // ---- merged epilogue ----
    __syncthreads();
    if (l1) {
      #pragma unroll
      for (int r = 0; r < 4; ++r)
        Sg1[(mt * 16 + quad * 4 + r) * 33 + nt * 16 + col] = a1[r];
    }
    if (l2) {
      #pragma unroll
      for (int r = 0; r < 4; ++r)
        Sg2[(mt * 16 + quad * 4 + r) * 33 + nt * 16 + col] = a2[r];
    }
    __syncthreads();
    if (l1) lstm_pw(Sg1, c1, h1n);
    if (l2) lstm_pw(Sg2, c2, h2n);
  };

  // small projection: out[m][j] = h2 . W[j] + b[j]  (region-layout h2 reads)
  auto out_phase = [&](const float* W, const float* bv, bool wout) {
    int j = bid & 63, mgp = bid >> 6;
    int rid = tid >> 4, ks = tid & 15;
    int mrow = mgp * 32 + rid;
    int mhp = mrow >> 6, mloc = mrow & 63;
    const float* wr = W + j * H_ + ks * 64;
    float s = 0.f;
    #pragma unroll
    for (int q = 0; q < 8; ++q) {
      int cgp = ks * 8 + q;                       // k-cols cgp*8..cgp*8+7
      half8 hv = *(const half8*)(h2c + (cgp * 2 + mhp) * 512 + mloc * 8);
      #pragma unroll
      for (int i = 0; i < 8; ++i) s += (float)hv[i] * wr[q * 8 + i];
    }
    s += __shfl_down(s, 8, 16);
    s += __shfl_down(s, 4, 16);
    s += __shfl_down(s, 2, 16);
    s += __shfl_down(s, 1, 16);
    if (ks == 0) {
      float v = s + bv[j];
      f16 hv = (f16)v;
      __hip_atomic_store((unsigned short*)&p.ob[mrow * 64 + j],
                         __builtin_bit_cast(unsigned short, hv),
                         __ATOMIC_RELAXED, __HIP_MEMORY_SCOPE_AGENT);
      if (wout) p.out[mrow * 64 + j] = v;
    }
  };

  // ---------------- time loop: 129 fused phases ----------------------------
  for (int t = -1; t < T_; ++t) {
    bool l1 = (t + 1 < T_), l2 = (t >= 0);
    phase(l1, l2, p.x16 + (t + 1) * DIN, T_ * DIN);
    gsync();
    if (l1) { f16* tm = h1c; h1c = h1n; h1n = tm; }
    if (l2) { f16* tm = h2c; h2c = h2n; h2n = tm; }
  }
  out_phase(p.Wlin, p.blin, fut == 0);
  gsync();
  for (int f = 0; f < fut; ++f) {
    phase(true, false, p.ob, 64);
    gsync();
    { f16* tm = h1c; h1c = h1n; h1n = tm; }
    phase(false, true, p.ob, 64);
    gsync();
    { f16* tm = h2c; h2c = h2n; h2n = tm; }
    out_phase(p.Whio, p.bhio, f == fut - 1);
    gsync();
  }
}

extern "C" void kernel_launch(void* const* d_in, const int* in_sizes, int n_in,
                              void* d_out, int out_size, void* d_ws, size_t ws_size,
                              hipStream_t stream) {
  char* w = (char*)d_ws;
  auto carve = [&](size_t n) { char* r = w; w += (n + 255) & ~(size_t)255; return r; };

  Params p;
  p.x    = (const float*)d_in[0];
  p.Wih1 = (const float*)d_in[1];
  p.Whh1 = (const float*)d_in[2];
  p.bih1 = (const float*)d_in[3];
  p.bhh1 = (const float*)d_in[4];
  p.Wih2 = (const float*)d_in[5];
  p.Whh2 = (const float*)d_in[6];
  p.bih2 = (const float*)d_in[7];
  p.bhh2 = (const float*)d_in[8];
  p.Wlin = (const float*)d_in[9];
  p.blin = (const float*)d_in[10];
  p.Whio = (const float*)d_in[11];
  p.bhio = (const float*)d_in[12];
  p.fut  = (const int*)d_in[13];
  p.out  = (float*)d_out;

  p.x16 = (f16*)carve((size_t)B_ * T_ * DIN * 2);
  p.h1a = (f16*)carve((size_t)B_ * H_ * 2);
  p.h1b = (f16*)carve((size_t)B_ * H_ * 2);
  p.h2a = (f16*)carve((size_t)B_ * H_ * 2);
  p.h2b = (f16*)carve((size_t)B_ * H_ * 2);
  p.ob  = (f16*)carve((size_t)B_ * 64 * 2);
  p.arrive = (unsigned*)carve(NBLK * sizeof(unsigned));
  p.rel    = (unsigned*)carve(256);
  p.S      = (unsigned*)carve(2048 * sizeof(unsigned));

  (void)hipFuncSetAttribute((const void*)lstm_k,
                            hipFuncAttributeMaxDynamicSharedMemorySize, SMEM_BYTES);
  void* args[] = { &p };
  (void)hipLaunchCooperativeKernel((void*)lstm_k, dim3(NBLK), dim3(NTHR),
                                   args, SMEM_BYTES, stream);
}

// Round 12
// 2194.751 us; speedup vs baseline: 1.3661x; 1.3661x over previous
//
#include <hip/hip_runtime.h>

#define B_   128
#define T_   128
#define DIN  64
#define H_   1024
#define NBLK 256
#define NTHR 512

typedef _Float16 f16;
typedef _Float16 half8 __attribute__((ext_vector_type(8)));
typedef float float4v __attribute__((ext_vector_type(4)));

// Work split: block b -> cg = b>>1 (8 h-cols: cg*8..cg*8+7), mh = b&1 (64 rows).
// h layout: region per block, h(m, col) at buf[b*512 + (m&63)*8 + (col&7)].
// Each block writes ONE contiguous 1KB region (exclusive lines, no RMW).
// Readers: window j, lane(col,quad): one dwordx4 at region (j*4+quad)*2+mh.
//
// LDS layout:
//  W1s : f16[2 nt][34 ch][512]   (Whh1 + Wih1 fragments)     69632 B
//  W2s : f16[2 nt][32 ch][512]   (Wih2 vs h1)                65536 B
//  Sg1 : float[64][33]                                        8448 B
//  Sg2 : float[64][33]                                        8448 B
//  c1,c2: float[512] each                                     4096 B
//  bs1,bs2: float[32] each                                     256 B   total 156416
// Whh2 (vs h2) lives in VGPRs (32 x half8) -- MUST be statically indexed
// (full unroll) or the compiler demotes it to scratch (R11 lesson: 4.4 GB
// of spill traffic, FETCH_SIZE exploded, dur +55%).
#define OFF_W2   69632
#define OFF_SG1  135168
#define OFF_SG2  143616
#define OFF_C1   152064
#define OFF_C2   154112
#define OFF_B1   156160
#define OFF_B2   156288
#define SMEM_BYTES 156416

// Barrier state S (unsigned[2048], 8 KB), one 128-B line per hot word:
//  S[x*32]         : per-XCD ticket
//  S[512]          : central XCD counter
//  S[544]          : release word            (polled by <=8 XCD leaders)
//  S[576 + x*32]   : per-XCD go flag         (polled by <=31 blocks)
//  S[1088 + x*32]  : per-XCD inv-done flag   (polled by 1 leader)
//  S[1600 + x]     : per-XCD block count     (preamble only)

struct Params {
  const float *x, *Wih1, *Whh1, *bih1, *bhh1, *Wih2, *Whh2, *bih2, *bhh2,
              *Wlin, *blin, *Whio, *bhio;
  const int* fut;
  float* out;
  f16 *x16, *h1a, *h1b, *h2a, *h2b, *ob;
  unsigned *arrive, *rel;
  unsigned *S;
};

__device__ __forceinline__ float sigm(float v) { return 1.f / (1.f + __expf(-v)); }
__device__ __forceinline__ float tanh_(float v) { return 2.f / (1.f + __expf(-2.f * v)) - 1.f; }

__device__ __forceinline__ unsigned get_xcc() {
  unsigned x;
  asm volatile("s_getreg_b32 %0, hwreg(HW_REG_XCC_ID)" : "=s"(x));
  return x & 15u;
}

// ---- slow barrier (preamble only) -----------------------------------------
__device__ __forceinline__ void grid_sync(unsigned* arrive, unsigned* rel, unsigned ph) {
  __syncthreads();
  const int tid = threadIdx.x, bid = blockIdx.x;
  if (bid == 0) {
    if (tid > 0 && tid < NBLK) {
      while (__hip_atomic_load(&arrive[tid], __ATOMIC_RELAXED, __HIP_MEMORY_SCOPE_AGENT) != ph)
        __builtin_amdgcn_s_sleep(8);
    }
    __syncthreads();
    if (tid == 0)
      __hip_atomic_store(rel, ph, __ATOMIC_RELEASE, __HIP_MEMORY_SCOPE_AGENT);
  } else {
    if (tid == 0) {
      __hip_atomic_store(&arrive[bid], ph, __ATOMIC_RELEASE, __HIP_MEMORY_SCOPE_AGENT);
      while (__hip_atomic_load(rel, __ATOMIC_RELAXED, __HIP_MEMORY_SCOPE_AGENT) != ph)
        __builtin_amdgcn_s_sleep(8);
    }
  }
  __syncthreads();
  __builtin_amdgcn_fence(__ATOMIC_ACQUIRE, "agent");
}

// ---- fast barrier v4 (R8/R10-proven): L2-inv hoisted to arrive-time -------
__device__ __forceinline__ void fast_sync(unsigned* S, unsigned x, unsigned xtotal,
                                          unsigned nxcd, unsigned ph) {
  __syncthreads();
  if (threadIdx.x == 0) {
    unsigned t = __hip_atomic_fetch_add(&S[x * 32], 1u, __ATOMIC_RELAXED, __HIP_MEMORY_SCOPE_AGENT);
    bool leader = (t % xtotal == 0u);
    if ((t + 1u) % xtotal == 0u) {
      unsigned c = __hip_atomic_fetch_add(&S[512], 1u, __ATOMIC_RELAXED, __HIP_MEMORY_SCOPE_AGENT);
      if ((c + 1u) % nxcd == 0u)
        __hip_atomic_store(&S[544], ph, __ATOMIC_RELAXED, __HIP_MEMORY_SCOPE_AGENT);
      asm volatile("buffer_inv sc0 sc1\n\ts_waitcnt vmcnt(0)" ::: "memory");
      __hip_atomic_store(&S[1088 + x * 32], ph, __ATOMIC_RELAXED, __HIP_MEMORY_SCOPE_AGENT);
    }
    if (leader) {
      while (__hip_atomic_load(&S[544], __ATOMIC_RELAXED, __HIP_MEMORY_SCOPE_AGENT) != ph)
        __builtin_amdgcn_s_sleep(1);
      while (__hip_atomic_load(&S[1088 + x * 32], __ATOMIC_RELAXED, __HIP_MEMORY_SCOPE_AGENT) != ph)
        __builtin_amdgcn_s_sleep(1);
      __hip_atomic_store(&S[576 + x * 32], ph, __ATOMIC_RELAXED, __HIP_MEMORY_SCOPE_AGENT);
      asm volatile("buffer_inv sc0\n\ts_waitcnt vmcnt(0)" ::: "memory");
    } else {
      while (__hip_atomic_load(&S[576 + x * 32], __ATOMIC_RELAXED, __HIP_MEMORY_SCOPE_AGENT) != ph)
        __builtin_amdgcn_s_sleep(2);
      asm volatile("buffer_inv sc0\n\ts_waitcnt vmcnt(0)" ::: "memory");
    }
  }
  __syncthreads();
}

__global__ void __launch_bounds__(NTHR, 2) lstm_k(Params p) {
  extern __shared__ char smem[];
  f16*   W1s  = (f16*)(smem);
  f16*   W2s  = (f16*)(smem + OFF_W2);
  float* Sg1  = (float*)(smem + OFF_SG1);
  float* Sg2  = (float*)(smem + OFF_SG2);
  float* c1   = (float*)(smem + OFF_C1);
  float* c2   = (float*)(smem + OFF_C2);
  float* bs1  = (float*)(smem + OFF_B1);
  float* bs2  = (float*)(smem + OFF_B2);

  const int tid = threadIdx.x, bid = blockIdx.x;
  const int cg  = bid >> 1;          // column group: h-cols cg*8..cg*8+7
  const int mh  = bid & 1;           // M-half: rows mh*64..mh*64+63
  const int fut = p.fut[0];
  const unsigned xcc = get_xcc();
  unsigned* S = p.S;

  // wave geometry
  const int lane = tid & 63, wv = tid >> 6;
  const int col = lane & 15, quad = lane >> 4;
  const int mt = wv & 3;             // m-tile within the 64-row half
  const int nt = wv >> 2;            // n-tile: gate-rows nt*16..nt*16+15
  const int mg = mh * 64 + mt * 16 + col;       // global batch row
  // h read base: region (j*4+quad)*2+mh, offset (mt*16+col)*8
  const int hbase = (quad * 2 + mh) * 512 + (mt * 16 + col) * 8;

  if (bid == 0) {
    for (int i = tid; i < 2048; i += NTHR)
      __hip_atomic_store(&S[i], 0u, __ATOMIC_RELAXED, __HIP_MEMORY_SCOPE_AGENT);
  }

  // ---------------- preamble ------------------------------------------------
  for (int idx = tid; idx < 2 * 34 * 512; idx += NTHR) {
    int ntl = idx / 17408, rem = idx - ntl * 17408;
    int c = rem >> 9, r = rem & 511;
    int q = r >> 7, colL = (r >> 3) & 15, j = r & 7;
    int k = c * 32 + q * 8 + j;
    int gr = ntl * 16 + colL;
    int row = (gr >> 3) * H_ + cg * 8 + (gr & 7);
    float v = (k < H_) ? p.Whh1[row * H_ + k] : p.Wih1[row * DIN + (k - H_)];
    W1s[idx] = (f16)v;
  }
  for (int idx = tid; idx < 2 * 32 * 512; idx += NTHR) {   // Wih2 (vs h1)
    int ntl = idx >> 14, rem = idx & 16383;
    int c = rem >> 9, r = rem & 511;
    int q = r >> 7, colL = (r >> 3) & 15, j = r & 7;
    int k = c * 32 + q * 8 + j;
    int gr = ntl * 16 + colL;
    int row = (gr >> 3) * H_ + cg * 8 + (gr & 7);
    W2s[idx] = (f16)p.Wih2[row * H_ + k];
  }
  // Whh2 -> registers (B-fragments for this wave's n-tile). Statically
  // indexed ONLY (full unroll at every use) else compiler spills to scratch.
  half8 wreg[32];
  {
    int gr = nt * 16 + col;
    int row2 = (gr >> 3) * H_ + cg * 8 + (gr & 7);
    const float* ws = p.Whh2 + row2 * H_ + quad * 8;
    #pragma unroll
    for (int c = 0; c < 32; ++c) {
      float4v v0 = *(const float4v*)(ws + c * 32);
      float4v v1 = *(const float4v*)(ws + c * 32 + 4);
      half8 t;
      t[0] = (f16)v0[0]; t[1] = (f16)v0[1]; t[2] = (f16)v0[2]; t[3] = (f16)v0[3];
      t[4] = (f16)v1[0]; t[5] = (f16)v1[1]; t[6] = (f16)v1[2]; t[7] = (f16)v1[3];
      wreg[c] = t;
    }
  }
  if (tid < 32) {
    int row = (tid >> 3) * H_ + cg * 8 + (tid & 7);
    bs1[tid] = p.bih1[row] + p.bhh1[row];
    bs2[tid] = p.bih2[row] + p.bhh2[row];
  }
  for (int i = tid; i < 512; i += NTHR) { c1[i] = 0.f; c2[i] = 0.f; }
  for (int i = bid * NTHR + tid; i < B_ * T_ * DIN; i += NBLK * NTHR)
    p.x16[i] = (f16)p.x[i];
  for (int i = bid * NTHR + tid; i < B_ * H_; i += NBLK * NTHR) {
    p.h1a[i] = (f16)0.f; p.h1b[i] = (f16)0.f;
    p.h2a[i] = (f16)0.f; p.h2b[i] = (f16)0.f;
  }

  unsigned ph = 1;
  grid_sync(p.arrive, p.rel, ph);
  if (tid == 0)
    __hip_atomic_fetch_add(&S[1600 + xcc], 1u, __ATOMIC_RELAXED, __HIP_MEMORY_SCOPE_AGENT);
  ++ph;
  grid_sync(p.arrive, p.rel, ph);

  unsigned xtotal = __hip_atomic_load(&S[1600 + xcc], __ATOMIC_RELAXED, __HIP_MEMORY_SCOPE_AGENT);
  unsigned nxcd = 0;
  for (int i = 0; i < 16; ++i)
    nxcd += (__hip_atomic_load(&S[1600 + i], __ATOMIC_RELAXED, __HIP_MEMORY_SCOPE_AGENT) != 0u);

  auto gsync = [&]() { ++ph; fast_sync(S, xcc, xtotal, nxcd, ph); };

  const float b1v = bs1[nt * 16 + col], b2v = bs2[nt * 16 + col];
  const f16* W1f = W1s + nt * (34 * 512) + lane * 8;
  const f16* W2f = W2s + nt * (32 * 512) + lane * 8;

  f16 *h1c = p.h1a, *h1n = p.h1b, *h2c = p.h2a, *h2n = p.h2b;

  auto ldwin = [&](const f16* hX, int j) -> half8 {
    return *(const half8*)(hX + hbase + j * 4096);
  };

  auto lstm_pw = [&](const float* Sgb, float* cst, f16* hn) {
    int r = tid >> 3, c8 = tid & 7;
    float gi = Sgb[r * 33 + c8],      gf = Sgb[r * 33 + 8 + c8];
    float gg = Sgb[r * 33 + 16 + c8], go = Sgb[r * 33 + 24 + c8];
    float cn = sigm(gf) * cst[tid] + sigm(gi) * tanh_(gg);
    cst[tid] = cn;
    f16 hv = (f16)(sigm(go) * tanh_(cn));
    __hip_atomic_store((unsigned short*)(hn + bid * 512 + tid),
                       __builtin_bit_cast(unsigned short, hv),
                       __ATOMIC_RELAXED, __HIP_MEMORY_SCOPE_AGENT);
  };

  // fused phase: gates1(t+1) [l1] and gates2(t) [l2], both keyed on h1c
  auto phase = [&](bool l1, bool l2, const f16* xp, int xstr) {
    float4v a1 = {b1v, b1v, b1v, b1v};
    float4v a2 = {b2v, b2v, b2v, b2v};

    if (l1) {   // x part (row-major, cached)
      half8 ax0 = *(const half8*)(xp + mg * xstr + quad * 8);
      half8 ax1 = *(const half8*)(xp + mg * xstr + 32 + quad * 8);
      a1 = __builtin_amdgcn_mfma_f32_16x16x32_f16(ax0, *(const half8*)(W1f + 32 * 512), a1, 0, 0, 0);
      a1 = __builtin_amdgcn_mfma_f32_16x16x32_f16(ax1, *(const half8*)(W1f + 33 * 512), a1, 0, 0, 0);
    }
    if (l1 && l2) {
      #pragma unroll 4
      for (int j = 0; j < 32; ++j) {
        half8 aw = ldwin(h1c, j);
        a1 = __builtin_amdgcn_mfma_f32_16x16x32_f16(aw, *(const half8*)(W1f + j * 512), a1, 0, 0, 0);
        a2 = __builtin_amdgcn_mfma_f32_16x16x32_f16(aw, *(const half8*)(W2f + j * 512), a2, 0, 0, 0);
      }
    } else if (l1) {
      #pragma unroll 4
      for (int j = 0; j < 32; ++j) {
        half8 aw = ldwin(h1c, j);
        a1 = __builtin_amdgcn_mfma_f32_16x16x32_f16(aw, *(const half8*)(W1f + j * 512), a1, 0, 0, 0);
      }
    } else {
      #pragma unroll 4
      for (int j = 0; j < 32; ++j) {
        half8 aw = ldwin(h1c, j);
        a2 = __builtin_amdgcn_mfma_f32_16x16x32_f16(aw, *(const half8*)(W2f + j * 512), a2, 0, 0, 0);
      }
    }
    if (l2) {   // h2 x Whh2: FULL unroll -> static wreg indices (no spill)
      #pragma unroll
      for (int j = 0; j < 32; ++j) {
        half8 aw = ldwin(h2c, j);
        a2 = __builtin_amdgcn_mfma_f32_16x16x32_f16(aw, wreg[j], a2, 0, 0, 0);
      }
    }

    // ---- merged epilogue ----
    __syncthreads();
    if (l1) {
      #pragma unroll
      for (int r = 0; r < 4; ++r)
        Sg1[(mt * 16 + quad * 4 + r) * 33 + nt * 16 + col] = a1[r];
    }
    if (l2) {
      #pragma unroll
      for (int r = 0; r < 4; ++r)
        Sg2[(mt * 16 + quad * 4 + r) * 33 + nt * 16 + col] = a2[r];
    }
    __syncthreads();
    if (l1) lstm_pw(Sg1, c1, h1n);
    if (l2) lstm_pw(Sg2, c2, h2n);
  };

  // small projection: out[m][j] = h2 . W[j] + b[j]  (region-layout h2 reads)
  auto out_phase = [&](const float* W, const float* bv, bool wout) {
    int j = bid & 63, mgp = bid >> 6;
    int rid = tid >> 4, ks = tid & 15;
    int mrow = mgp * 32 + rid;
    int mhp = mrow >> 6, mloc = mrow & 63;
    const float* wr = W + j * H_ + ks * 64;
    float s = 0.f;
    #pragma unroll
    for (int q = 0; q < 8; ++q) {
      int cgp = ks * 8 + q;
      half8 hv = *(const half8*)(h2c + (cgp * 2 + mhp) * 512 + mloc * 8);
      #pragma unroll
      for (int i = 0; i < 8; ++i) s += (float)hv[i] * wr[q * 8 + i];
    }
    s += __shfl_down(s, 8, 16);
    s += __shfl_down(s, 4, 16);
    s += __shfl_down(s, 2, 16);
    s += __shfl_down(s, 1, 16);
    if (ks == 0) {
      float v = s + bv[j];
      f16 hv = (f16)v;
      __hip_atomic_store((unsigned short*)&p.ob[mrow * 64 + j],
                         __builtin_bit_cast(unsigned short, hv),
                         __ATOMIC_RELAXED, __HIP_MEMORY_SCOPE_AGENT);
      if (wout) p.out[mrow * 64 + j] = v;
    }
  };

  // ---------------- time loop: 129 fused phases ----------------------------
  for (int t = -1; t < T_; ++t) {
    bool l1 = (t + 1 < T_), l2 = (t >= 0);
    phase(l1, l2, p.x16 + (t + 1) * DIN, T_ * DIN);
    gsync();
    if (l1) { f16* tm = h1c; h1c = h1n; h1n = tm; }
    if (l2) { f16* tm = h2c; h2c = h2n; h2n = tm; }
  }
  out_phase(p.Wlin, p.blin, fut == 0);
  gsync();
  for (int f = 0; f < fut; ++f) {
    phase(true, false, p.ob, 64);
    gsync();
    { f16* tm = h1c; h1c = h1n; h1n = tm; }
    phase(false, true, p.ob, 64);
    gsync();
    { f16* tm = h2c; h2c = h2n; h2n = tm; }
    out_phase(p.Whio, p.bhio, f == fut - 1);
    gsync();
  }
}

extern "C" void kernel_launch(void* const* d_in, const int* in_sizes, int n_in,
                              void* d_out, int out_size, void* d_ws, size_t ws_size,
                              hipStream_t stream) {
  char* w = (char*)d_ws;
  auto carve = [&](size_t n) { char* r = w; w += (n + 255) & ~(size_t)255; return r; };

  Params p;
  p.x    = (const float*)d_in[0];
  p.Wih1 = (const float*)d_in[1];
  p.Whh1 = (const float*)d_in[2];
  p.bih1 = (const float*)d_in[3];
  p.bhh1 = (const float*)d_in[4];
  p.Wih2 = (const float*)d_in[5];
  p.Whh2 = (const float*)d_in[6];
  p.bih2 = (const float*)d_in[7];
  p.bhh2 = (const float*)d_in[8];
  p.Wlin = (const float*)d_in[9];
  p.blin = (const float*)d_in[10];
  p.Whio = (const float*)d_in[11];
  p.bhio = (const float*)d_in[12];
  p.fut  = (const int*)d_in[13];
  p.out  = (float*)d_out;

  p.x16 = (f16*)carve((size_t)B_ * T_ * DIN * 2);
  p.h1a = (f16*)carve((size_t)B_ * H_ * 2);
  p.h1b = (f16*)carve((size_t)B_ * H_ * 2);
  p.h2a = (f16*)carve((size_t)B_ * H_ * 2);
  p.h2b = (f16*)carve((size_t)B_ * H_ * 2);
  p.ob  = (f16*)carve((size_t)B_ * 64 * 2);
  p.arrive = (unsigned*)carve(NBLK * sizeof(unsigned));
  p.rel    = (unsigned*)carve(256);
  p.S      = (unsigned*)carve(2048 * sizeof(unsigned));

  (void)hipFuncSetAttribute((const void*)lstm_k,
                            hipFuncAttributeMaxDynamicSharedMemorySize, SMEM_BYTES);
  void* args[] = { &p };
  (void)hipLaunchCooperativeKernel((void*)lstm_k, dim3(NBLK), dim3(NTHR),
                                   args, SMEM_BYTES, stream);
}